// Round 4
// baseline (177.944 us; speedup 1.0000x reference)
//
#include <hip/hip_runtime.h>
#include <hip/hip_bf16.h>
#include <cstdint>

#define B_ 4
#define H_ 80
#define W_ 80
#define CH_ 256
#define NC_ 22
#define DIM_ 256
#define NPIX (B_*H_*W_)

typedef unsigned short ushort;
typedef __attribute__((ext_vector_type(8))) short short8;     // 8 bf16 = 4 VGPR
typedef __attribute__((ext_vector_type(4))) float floatx4;    // MFMA C/D frag

static __device__ inline ushort f2bf(float v) {
    __hip_bfloat16 h = __float2bfloat16(v);   // RNE
    ushort r;
    __builtin_memcpy(&r, &h, 2);
    return r;
}
static __device__ inline unsigned pk2(float a, float b) {
    return (unsigned)f2bf(a) | ((unsigned)f2bf(b) << 16);
}

// async global->LDS, 16 B per lane; LDS dest = wave-uniform base + lane*16
static __device__ inline void gll16(const ushort* g, ushort* l) {
    __builtin_amdgcn_global_load_lds(
        (const __attribute__((address_space(1))) unsigned int*)g,
        (__attribute__((address_space(3))) unsigned int*)l, 16, 0, 0);
}

// ---------------------------------------------------------------------------
// prep: blocks 0..71  -> weight repack cw[c][k][d] f32 -> wbT[k][d][c] bf16
//       blocks 72..3271 -> x f32 -> xb bf16 (+ 1KB zero pad after xb)
// ---------------------------------------------------------------------------
__global__ __launch_bounds__(256) void prep(const float* __restrict__ cw,
                                            const float* __restrict__ x,
                                            ushort* __restrict__ wbT,
                                            ushort* __restrict__ xb)
{
    __shared__ ushort ls[32][260];
    if (blockIdx.x >= 72) {
        const int bid = blockIdx.x - 72;
        const size_t idx = ((size_t)bid * 256 + threadIdx.x) * 8;
        const float4* s = (const float4*)(x + idx);
        float4 a = s[0], b = s[1];
        *(uint4*)(xb + idx) = make_uint4(pk2(a.x, a.y), pk2(a.z, a.w),
                                         pk2(b.x, b.y), pk2(b.z, b.w));
        if (bid == 0 && threadIdx.x < 64)   // zero pad region (1 KB)
            *(uint4*)(xb + (size_t)NPIX * CH_ + threadIdx.x * 8) = make_uint4(0, 0, 0, 0);
        return;
    }
    const int k  = blockIdx.x / 8;
    const int c0 = (blockIdx.x % 8) * 32;
    const int c   = threadIdx.x >> 3;        // 0..31
    const int sg  = threadIdx.x & 7;         // 0..7

    const float* src = cw + ((size_t)(c0 + c) * 9 + k) * DIM_ + sg * 32;
    #pragma unroll
    for (int e = 0; e < 32; e += 4) {
        float4 v = *(const float4*)(src + e);
        unsigned* dst = (unsigned*)&ls[c][sg * 32 + e];
        dst[0] = pk2(v.x, v.y);
        dst[1] = pk2(v.z, v.w);
    }
    __syncthreads();

    const int d = threadIdx.x;
    ushort tmp[32];
    #pragma unroll
    for (int cc = 0; cc < 32; ++cc) tmp[cc] = ls[cc][d];
    uint4 o[4];
    __builtin_memcpy(o, tmp, 64);
    uint4* dst = (uint4*)(wbT + ((size_t)k * 256 + d) * 256 + c0);
    dst[0] = o[0]; dst[1] = o[1]; dst[2] = o[2]; dst[3] = o[3];
}

// ---------------------------------------------------------------------------
// conv3: block = image row (80 px) x 128 d.  grid (2, 320): x = d-half (L2
// locality: adjacent blocks share the row), y = b*H+h.  4 waves, wave-tile
// 80x32.  6 phases (i=0..2 x cc={0,128}); per phase stage halo'd A-tile
// (84 rows x 128 ch bf16, XOR-swizzled, via global_load_lds) ONCE, then 3
// taps (j=0,1,2; k=3i+j) of 40 MFMAs each read it at col-offset j.
// B: 8 short8 regs per tap, straight from L2-hot wbT.  Per-tap scale s_k[m]
// applied on the C-fragment (fp32).  One barrier per phase.
// ---------------------------------------------------------------------------
__global__ __launch_bounds__(256, 3) void conv3(const ushort* __restrict__ xb,
                                                const float* __restrict__ seg,
                                                const ushort* __restrict__ wbT,
                                                float* __restrict__ out)
{
    __shared__ ushort xs[2][84 * 128];    // 43 KB, row stride 256 B, swizzled
    __shared__ float  sl[9][80];          // 2.88 KB

    const int tid  = threadIdx.x;
    const int lane = tid & 63;
    const int wv   = tid >> 6;
    const int ln   = lane & 15;
    const int quad = lane >> 4;
    const int d0   = blockIdx.x * 128;
    const int rt   = blockIdx.y;          // b*H + h
    const int b    = rt / H_;
    const int h    = rt % H_;
    const ushort* zpad = xb + (size_t)NPIX * CH_;

    // ---- async stage of phase p into buffer buf ----
    // LDS slot (rho, c') holds global chunk (c'&8)|((c'^rho)&7)  (involution)
    const int rho0 = lane >> 4;           // 0..3 within a 4-row group
    const int cp   = lane & 15;
    auto stage = [&](int p, int buf) {
        const int i  = p >> 1;
        const int cc = (p & 1) * 128;
        const int r  = h + i - 1;
        const bool rowok = (r >= 0) && (r < H_);
        for (int g = wv; g < 21; g += 4) {
            const int rho = g * 4 + rho0;
            const int scn = (cp & 8) | ((cp ^ rho) & 7);
            const int col = rho - 1;
            const bool v = rowok && (col >= 0) && (col < W_);
            const ushort* src = v ? (xb + (((size_t)(b * H_ + r)) * W_ + col) * CH_
                                        + cc + scn * 8)
                                  : zpad;
            gll16(src, &xs[buf][g * 512]);
        }
    };

    stage(0, 0);                          // phase-0 A in flight

    // ---- fused sel: threads 0..79 compute ssel for this row into sl ----
    if (tid < W_) {
        const int m = tid;
        const float2* c2 = (const float2*)(seg + ((size_t)(b * H_ + h) * W_ + m) * NC_);
        float cv[NC_];
        #pragma unroll
        for (int c = 0; c < NC_ / 2; ++c) { float2 v = c2[c]; cv[2*c] = v.x; cv[2*c+1] = v.y; }
        float mx = -1e30f;
        #pragma unroll
        for (int c = 0; c < NC_; ++c) mx = fmaxf(mx, cv[c]);
        float sel[9];
        int cnt = 0;
        #pragma unroll
        for (int k = 0; k < 9; ++k) {
            int i = k / 3, j = k % 3;
            int hh = h + i - 1, ww = m + j - 1;
            float s = 0.f;
            if (hh >= 0 && hh < H_ && ww >= 0 && ww < W_) {
                const float2* n2 = (const float2*)(seg + ((size_t)(b * H_ + hh) * W_ + ww) * NC_);
                #pragma unroll
                for (int c = 0; c < NC_ / 2; ++c) {
                    float2 v = n2[c];
                    s += (cv[2*c]   == mx) ? v.x : 0.f;
                    s += (cv[2*c+1] == mx) ? v.y : 0.f;
                }
            }
            sel[k] = s;
            cnt += (s != 0.f) ? 1 : 0;
        }
        float norm = (cnt > 0) ? 9.f / (float)cnt : 0.f;
        #pragma unroll
        for (int k = 0; k < 9; ++k) sl[k][m] = sel[k] * norm;
    }

    floatx4 O[5][2];
    #pragma unroll
    for (int im = 0; im < 5; ++im)
        #pragma unroll
        for (int jn = 0; jn < 2; ++jn)
            O[im][jn] = (floatx4){0.f, 0.f, 0.f, 0.f};

    __syncthreads();                      // drains gll(phase0) + sel LDS writes

    for (int p = 0; p < 6; ++p) {
        const int buf = p & 1;
        const int i   = p >> 1;
        const int cc  = (p & 1) * 128;
        if (p < 5) stage(p + 1, buf ^ 1); // next phase's A in flight during MFMA

        #pragma unroll
        for (int j = 0; j < 3; ++j) {
            const int k = 3 * i + j;

            short8 Breg[8];               // [kk][jn]
            #pragma unroll
            for (int kk = 0; kk < 4; ++kk)
                #pragma unroll
                for (int jn = 0; jn < 2; ++jn)
                    Breg[kk * 2 + jn] = *(const short8*)(wbT
                        + ((size_t)k * 256 + d0 + wv * 32 + jn * 16 + ln) * 256
                        + cc + kk * 32 + quad * 8);

            floatx4 P[5][2];
            #pragma unroll
            for (int im = 0; im < 5; ++im)
                #pragma unroll
                for (int jn = 0; jn < 2; ++jn)
                    P[im][jn] = (floatx4){0.f, 0.f, 0.f, 0.f};

            #pragma unroll
            for (int kk = 0; kk < 4; ++kk) {
                short8 a[5];
                #pragma unroll
                for (int im = 0; im < 5; ++im) {
                    const int rho = im * 16 + ln + j;
                    const int Gc  = 4 * kk + quad;
                    const int ch  = (Gc & 8) | ((Gc ^ rho) & 7);
                    a[im] = *(const short8*)&xs[buf][rho * 128 + ch * 8];
                }
                #pragma unroll
                for (int im = 0; im < 5; ++im)
                    #pragma unroll
                    for (int jn = 0; jn < 2; ++jn)
                        P[im][jn] = __builtin_amdgcn_mfma_f32_16x16x32_bf16(
                            a[im], Breg[kk * 2 + jn], P[im][jn], 0, 0, 0);
            }

            // O += s_k[m] * P   (row m = im*16 + quad*4 + e; broadcast LDS read)
            #pragma unroll
            for (int im = 0; im < 5; ++im) {
                const floatx4 sv = *(const floatx4*)&sl[k][im * 16 + quad * 4];
                #pragma unroll
                for (int jn = 0; jn < 2; ++jn) {
                    O[im][jn][0] += sv[0] * P[im][jn][0];
                    O[im][jn][1] += sv[1] * P[im][jn][1];
                    O[im][jn][2] += sv[2] * P[im][jn][2];
                    O[im][jn][3] += sv[3] * P[im][jn][3];
                }
            }
        }
        __syncthreads();                  // buf consumed + next-phase gll drained
    }

    // epilogue: C/D layout col(d)=lane&15, row(m)=quad*4+reg
    #pragma unroll
    for (int im = 0; im < 5; ++im) {
        #pragma unroll
        for (int jn = 0; jn < 2; ++jn) {
            const int dd = d0 + wv * 32 + jn * 16 + ln;
            #pragma unroll
            for (int r = 0; r < 4; ++r) {
                const int m = im * 16 + quad * 4 + r;
                out[((size_t)(rt * W_ + m)) * DIM_ + dd] = O[im][jn][r];
            }
        }
    }
}

extern "C" void kernel_launch(void* const* d_in, const int* in_sizes, int n_in,
                              void* d_out, int out_size, void* d_ws, size_t ws_size,
                              hipStream_t stream)
{
    const float* x   = (const float*)d_in[0];   // (4,80,80,256) f32
    const float* seg = (const float*)d_in[1];   // (4,80,80,22)  f32
    const float* cw  = (const float*)d_in[2];   // (256,3,3,256) f32
    float* out = (float*)d_out;

    ushort* wbT = (ushort*)d_ws;                           // 9*256*256*2 = 1179648 B
    ushort* xb  = (ushort*)((char*)d_ws + 1179648);        // 13107200 B + 1 KB pad

    prep<<<dim3(72 + NPIX * CH_ / (256 * 8)), dim3(256), 0, stream>>>(cw, x, wbT, xb);
    conv3<<<dim3(2, B_ * H_), dim3(256), 0, stream>>>(xb, seg, wbT, out);
}